// Round 10
// baseline (140.825 us; speedup 1.0000x reference)
//
#include <hip/hip_runtime.h>

namespace {
constexpr float SCALE = 0.17677669529663687f; // 32^-0.5
// LDS layout: SLOT-OUTER ring — buf[slot][ch][64 px], slot=0..3, ch=0..31.
// slot*2048 and ch*64 are both = 0 mod 32 banks, so bank = stored_px % 32:
// identical to the verified zero-conflict rotation bijection. Slot-outer makes
// the 2 dying slots a CONTIGUOUS 1024-f4 region -> ring staging is lane-linear
// (l4 = s0*512 + idx), satisfying global_load_lds' wave-uniform-base+lane*16
// destination rule (m104) — this was the round-8/9 correctness bug.

typedef const __attribute__((address_space(1))) void gbl_v;
typedef __attribute__((address_space(3))) void lds_v;
typedef float v2f __attribute__((ext_vector_type(2)));   // -> v_pk_fma_f32

// quad_perm DPP xor-permute (VALU, no LDS pipe): 0xB1 = lane^1, 0x4E = lane^2
template<int CTRL>
__device__ __forceinline__ float qperm(float v) {
  return __builtin_bit_cast(float, __builtin_amdgcn_mov_dpp(
      __builtin_bit_cast(int, v), CTRL, 0xF, 0xF, true));
}

#define VMW0    asm volatile("s_waitcnt vmcnt(0)" ::: "memory")
#define LKW0    asm volatile("s_waitcnt lgkmcnt(0)" ::: "memory")
#define FENCE() asm volatile("" ::: "memory")

// Block = (image b, head, 8-row same-parity chunk) run as a 4-iteration
// pipeline over row pairs {rt, rt+2}, rt = R0+4t. K/V live in 4-row-slot RING
// buffers, slot(row) = ((row-R0)/2+1)&3; each iteration stages only the 2 NEW
// rows (rt+6 -> slot 2t&3, rt+8 -> slot (2t+1)&3 — adjacent, contiguous).
//
// Conservative sync (correct under ANY vmcnt retirement order):
//   A: vmcnt(0) + s_barrier  -> K_t and V_t staged & visible; QK from ring
//   B: lgkmcnt(0) + s_barrier (K ds_reads done, WAR) -> stage K_{t+1};
//      reduce(DPP)+softmax; PV; store
//   C: lgkmcnt(0) + s_barrier (PV reads done) -> q_{t+1}; stage V_{t+1}
// V_t issues at C, drains at next A (latency hidden under q-loads + A of the
// next iter); K_t has a full iteration of cover. Structural wins: 512 blocks
// (not 2048), prologue amortized 4x, staging 10 rows per 8 query rows.
__global__ __launch_bounds__(512, 4) void dilate_attn(
    const float* __restrict__ q, const float* __restrict__ k,
    const float* __restrict__ v, float* __restrict__ out) {
  __shared__ float kbuf[4 * 2048];   // 32768 B, [slot][ch][64]
  __shared__ float vbuf[4 * 2048];   // 32768 B

  const int tid = threadIdx.x;
  const int cg  = tid & 7;           // 4-channel group
  const int pp  = (tid >> 3) & 31;   // pixel pair (px0 = 2*pp)
  const int rg  = tid >> 8;          // query row within pair

  // XCD swizzle: blk&7 -> XCD; 8 consecutive same-XCD blocks = one (b,head)
  // = 1 MB of k/v streaming through that XCD's L2 with chunk-halo reuse.
  const int blk   = blockIdx.x;               // 0..511
  const int xcd   = blk & 7;
  const int m     = blk >> 3;                 // 0..63
  const int combo = (xcd << 3) | (m >> 3);    // (b,head), 8 per XCD
  const int ck    = m & 7;                    // parity*4 + chunk
  const int p     = ck >> 2;
  const int c     = ck & 3;
  const int R0    = p + (c << 4);             // chunk base row
  const int b     = combo >> 2;
  const int head  = combo & 3;

  const size_t cb = ((size_t)b * 128 + head * 32) * 4096;
  const float* kp = k + cb;
  const float* vp = v + cb;
  const float* qp = q + cb;

  // column taps (clamped, even) + x masks; per-channel rotation rot = 4*cg
  const int px0 = pp << 1;
  const int   txL = (pp == 0)  ? 0  : px0 - 2;
  const int   txC = px0;
  const int   txR = (pp == 31) ? 62 : px0 + 2;
  const float mL  = (pp == 0)  ? 0.0f : 1.0f;
  const float mR  = (pp == 31) ? 0.0f : 1.0f;
  const int rot = cg << 2;
  const int tL  = (txL + rot) & 63;
  const int tC  = (txC + rot) & 63;
  const int tR  = (txR + rot) & 63;

  // ---------- prologue: stage K slots 0..3 (rows R0-2..R0+4), q(iter0), V ----------
  // idx = slot*512 + ch*16 + q4 -> l4 = idx exactly (lane-linear).
  #pragma unroll
  for (int u = 0; u < 4; ++u) {
    const int idx = u * 512 + tid;           // f4 slot 0..2047
    const int sl  = idx >> 9;
    const int ch  = (idx >> 4) & 31;
    const int q4  = idx & 15;
    int row = R0 - 2 + 2 * sl;
    row = row < 0 ? 0 : row;
    const int pxs = ((q4 - (ch >> 2)) & 15) << 2;
    __builtin_amdgcn_global_load_lds((gbl_v*)(kp + ch * 4096 + row * 64 + pxs),
                                     (lds_v*)(kbuf + (idx << 2)), 16, 0, 0);
  }
  FENCE();
  v2f q2[4];
  #pragma unroll
  for (int ci = 0; ci < 4; ++ci) {
    q2[ci] = *(const v2f*)(qp + (cg * 4 + ci) * 4096 + (R0 + 2 * rg) * 64 + px0);
    q2[ci] *= SCALE;
  }
  FENCE();
  #pragma unroll
  for (int u = 0; u < 4; ++u) {
    const int idx = u * 512 + tid;
    const int sl  = idx >> 9;
    const int ch  = (idx >> 4) & 31;
    const int q4  = idx & 15;
    int row = R0 - 2 + 2 * sl;
    row = row < 0 ? 0 : row;
    const int pxs = ((q4 - (ch >> 2)) & 15) << 2;
    __builtin_amdgcn_global_load_lds((gbl_v*)(vp + ch * 4096 + row * 64 + pxs),
                                     (lds_v*)(vbuf + (idx << 2)), 16, 0, 0);
  }
  FENCE();

  // ---------- 4-iteration pipeline ----------
  #pragma unroll
  for (int t = 0; t < 4; ++t) {
    const int rt   = R0 + 4 * t;
    const int qrow = rt + 2 * rg;

    // ---- A: all prior staging (K_t, V_t) retired, then cross-wave sync ----
    VMW0;
    __builtin_amdgcn_s_barrier();
    FENCE();

    // ---- QK over this thread's 4 channels (ring slots, pk_fma) ----
    v2f l[9];
    #pragma unroll
    for (int i = 0; i < 9; ++i) l[i] = (v2f)(0.0f);
    #pragma unroll
    for (int r = 0; r < 3; ++r) {
      const int slot = (2 * t + rg + r) & 3;
      #pragma unroll
      for (int ci = 0; ci < 4; ++ci) {
        const float* kc = kbuf + slot * 2048 + (cg * 4 + ci) * 64;
        l[r*3+0] = __builtin_elementwise_fma(q2[ci], *(const v2f*)(kc + tL), l[r*3+0]);
        l[r*3+1] = __builtin_elementwise_fma(q2[ci], *(const v2f*)(kc + tC), l[r*3+1]);
        l[r*3+2] = __builtin_elementwise_fma(q2[ci], *(const v2f*)(kc + tR), l[r*3+2]);
      }
    }

    // ---- B: all waves' K ds_reads done -> safe to overwrite dying K slots ----
    LKW0;
    __builtin_amdgcn_s_barrier();
    FENCE();
    if (t < 3) {
      const int s0 = (t & 1) << 1;           // dying slots {s0, s0+1}
      #pragma unroll
      for (int u = 0; u < 2; ++u) {
        const int idx = u * 512 + tid;       // 0..1023 within the 2-slot region
        const int so  = idx >> 9;            // 0|1 (wave-uniform)
        const int ch  = (idx >> 4) & 31;
        const int q4  = idx & 15;
        int row = rt + 6 + 2 * so;           // slot s0+so <- row rt+6+2*so
        row = row > 63 ? 63 : row;
        const int pxs = ((q4 - (ch >> 2)) & 15) << 2;
        const int l4  = s0 * 512 + idx;      // lane-linear (s0 wave-uniform)
        __builtin_amdgcn_global_load_lds((gbl_v*)(kp + ch * 4096 + row * 64 + pxs),
                                         (lds_v*)(kbuf + (l4 << 2)), 16, 0, 0);
      }
      FENCE();
    }

    // ---- reduce 8 cg-partials: xor1, xor2 via DPP; xor4 via shuffle ----
    #pragma unroll
    for (int i = 0; i < 9; ++i) { l[i].x += qperm<0xB1>(l[i].x); l[i].y += qperm<0xB1>(l[i].y); }
    #pragma unroll
    for (int i = 0; i < 9; ++i) { l[i].x += qperm<0x4E>(l[i].x); l[i].y += qperm<0x4E>(l[i].y); }
    #pragma unroll
    for (int i = 0; i < 9; ++i) {
      l[i].x += __shfl_xor(l[i].x, 4, 64);
      l[i].y += __shfl_xor(l[i].y, 4, 64);
    }

    // ---- softmax over 9 (masked taps -> e^0 = 1, matching zero-pad ref) ----
    float msk[9];
    #pragma unroll
    for (int r = 0; r < 3; ++r) {
      const int row = qrow - 2 + 2 * r;
      const float vmr = ((unsigned)row < 64u) ? 1.0f : 0.0f;
      msk[r*3+0] = vmr * mL; msk[r*3+1] = vmr; msk[r*3+2] = vmr * mR;
    }
    v2f sum = (v2f)(0.0f);
    #pragma unroll
    for (int i = 0; i < 9; ++i) {
      l[i] *= msk[i];
      l[i].x = __expf(l[i].x);
      l[i].y = __expf(l[i].y);
      sum += l[i];
    }
    v2f rv; rv.x = 1.0f / sum.x; rv.y = 1.0f / sum.y;
    #pragma unroll
    for (int i = 0; i < 9; ++i) l[i] *= rv * msk[i];  // fold V zero-pad in

    // ---- PV from vbuf ring slots (pk_fma) ----
    v2f o[4];
    #pragma unroll
    for (int ci = 0; ci < 4; ++ci) o[ci] = (v2f)(0.0f);
    #pragma unroll
    for (int r = 0; r < 3; ++r) {
      const int slot = (2 * t + rg + r) & 3;
      #pragma unroll
      for (int ci = 0; ci < 4; ++ci) {
        const float* vc = vbuf + slot * 2048 + (cg * 4 + ci) * 64;
        o[ci] = __builtin_elementwise_fma(l[r*3+0], *(const v2f*)(vc + tL), o[ci]);
        o[ci] = __builtin_elementwise_fma(l[r*3+1], *(const v2f*)(vc + tC), o[ci]);
        o[ci] = __builtin_elementwise_fma(l[r*3+2], *(const v2f*)(vc + tR), o[ci]);
      }
    }

    // ---- store: 8 px x 128B contiguous per wave-instr ----
    float* ob = out + ((size_t)(b * 64 + qrow) * 64 + px0) * 128 + head * 32 + cg * 4;
    *(float4*)(ob)       = make_float4(o[0].x, o[1].x, o[2].x, o[3].x);
    *(float4*)(ob + 128) = make_float4(o[0].y, o[1].y, o[2].y, o[3].y);

    if (t < 3) {
      // ---- C: all waves' V ds_reads done -> safe to overwrite dying V slots ----
      LKW0;
      __builtin_amdgcn_s_barrier();
      FENCE();
      // next q (issued before V-stage; consumed after next A)
      #pragma unroll
      for (int ci = 0; ci < 4; ++ci) {
        q2[ci] = *(const v2f*)(qp + (cg * 4 + ci) * 4096 + (qrow + 4) * 64 + px0);
        q2[ci] *= SCALE;
      }
      FENCE();
      const int s0 = (t & 1) << 1;
      #pragma unroll
      for (int u = 0; u < 2; ++u) {
        const int idx = u * 512 + tid;
        const int so  = idx >> 9;
        const int ch  = (idx >> 4) & 31;
        const int q4  = idx & 15;
        int row = rt + 6 + 2 * so;
        row = row > 63 ? 63 : row;
        const int pxs = ((q4 - (ch >> 2)) & 15) << 2;
        const int l4  = s0 * 512 + idx;
        __builtin_amdgcn_global_load_lds((gbl_v*)(vp + ch * 4096 + row * 64 + pxs),
                                         (lds_v*)(vbuf + (l4 << 2)), 16, 0, 0);
      }
      FENCE();
    }
  }
}
} // namespace

extern "C" void kernel_launch(void* const* d_in, const int* in_sizes, int n_in,
                              void* d_out, int out_size, void* d_ws, size_t ws_size,
                              hipStream_t stream) {
  const float* q = (const float*)d_in[0];
  const float* k = (const float*)d_in[1];
  const float* v = (const float*)d_in[2];
  float* o = (float*)d_out;
  // 16 b x 4 heads x 2 parities x 4 chunks = 512 blocks x 4 row-pairs each
  dilate_attn<<<dim3(512), dim3(512), 0, stream>>>(q, k, v, o);
}